// Round 1
// baseline (208.791 us; speedup 1.0000x reference)
//
#include <hip/hip_runtime.h>

#define B_ 8
#define D_ 256
#define N_ 32768
#define F_ 256
#define K_ 16

// ---------------------------------------------------------------------------
// K1: sims[b][n] = -(q[b,:] . keys[b,:,n]) / 16
// grid = 8 b * 32 chunks = 256 blocks, 256 threads, 4 n per thread (float4)
// ---------------------------------------------------------------------------
__global__ __launch_bounds__(256) void sims_kernel(
    const float* __restrict__ q, const float* __restrict__ keys,
    float* __restrict__ sims) {
  const int b = blockIdx.x >> 5;
  const int chunk = blockIdx.x & 31;
  const int t = threadIdx.x;
  __shared__ float qs[D_];
  qs[t] = q[b * D_ + t];
  __syncthreads();
  const int n0 = (chunk * 256 + t) * 4;
  const float* kp = keys + (size_t)b * D_ * N_ + n0;
  float ax = 0.f, ay = 0.f, az = 0.f, aw = 0.f;
#pragma unroll 8
  for (int d = 0; d < D_; ++d) {
    float4 kv = *reinterpret_cast<const float4*>(kp + (size_t)d * N_);
    float qd = qs[d];
    ax += qd * kv.x; ay += qd * kv.y; az += qd * kv.z; aw += qd * kv.w;
  }
  float4 o;
  o.x = -0.0625f * ax; o.y = -0.0625f * ay;
  o.z = -0.0625f * az; o.w = -0.0625f * aw;
  *reinterpret_cast<float4*>(sims + (size_t)b * N_ + n0) = o;
}

// ---------------------------------------------------------------------------
// K2: softmax cascade. One block (1024 threads) per batch, alpha in registers.
// omega layout: [B][K][N] (n fastest) so stores are coalesced per step.
// ---------------------------------------------------------------------------
__device__ __forceinline__ float block_allreduce(float v, bool is_max,
                                                 float* red) {
  const int t = threadIdx.x;
#pragma unroll
  for (int off = 32; off > 0; off >>= 1) {
    float o = __shfl_xor(v, off, 64);
    v = is_max ? fmaxf(v, o) : (v + o);
  }
  __syncthreads();  // previous use of red finished
  if ((t & 63) == 0) red[t >> 6] = v;
  __syncthreads();
  if (t == 0) {
    float x = red[0];
#pragma unroll
    for (int w = 1; w < 16; ++w) x = is_max ? fmaxf(x, red[w]) : (x + red[w]);
    red[16] = x;
  }
  __syncthreads();
  return red[16];
}

__global__ __launch_bounds__(1024) void cascade_kernel(
    const float* __restrict__ sims, float* __restrict__ omega) {
  const int b = blockIdx.x;
  const int t = threadIdx.x;
  const float* s = sims + (size_t)b * N_;
  float* om_b = omega + (size_t)b * K_ * N_;
  __shared__ float red[17];

  float alpha[32];
#pragma unroll
  for (int j = 0; j < 32; ++j) alpha[j] = s[t + j * 1024];

  // alpha = softmax(sims)
  {
    float m = -1e30f;
#pragma unroll
    for (int j = 0; j < 32; ++j) m = fmaxf(m, alpha[j]);
    m = block_allreduce(m, true, red);
    float sum = 0.f;
#pragma unroll
    for (int j = 0; j < 32; ++j) { alpha[j] = __expf(alpha[j] - m); sum += alpha[j]; }
    sum = block_allreduce(sum, false, red);
    const float inv = 1.0f / sum;
#pragma unroll
    for (int j = 0; j < 32; ++j) alpha[j] *= inv;
  }

  // 16 cascade steps: om = softmax(alpha); alpha += log(1 - om)
  // om <= ~3.1e-5 always (near-uniform softmax over 32768), so
  // log1p(-om) = -(om + om^2/2) exactly to ~1e-14.
  for (int k = 0; k < K_; ++k) {
    float m = -1e30f;
#pragma unroll
    for (int j = 0; j < 32; ++j) m = fmaxf(m, alpha[j]);
    m = block_allreduce(m, true, red);
    float e[32];
    float sum = 0.f;
#pragma unroll
    for (int j = 0; j < 32; ++j) { e[j] = __expf(alpha[j] - m); sum += e[j]; }
    sum = block_allreduce(sum, false, red);
    const float inv = 1.0f / sum;
    float* op = om_b + (size_t)k * N_;
#pragma unroll
    for (int j = 0; j < 32; ++j) {
      float om = e[j] * inv;
      op[t + j * 1024] = om;
      alpha[j] -= om + 0.5f * om * om;
    }
  }
}

// ---------------------------------------------------------------------------
// K3: out[b][k][f] = sum_n omega[b][k][n] * values[b][f][n]
// grid = 512 blocks: b = blockIdx&7 (XCD affinity for omega L2 reuse),
// fgroup = blockIdx>>3 (4 f each). 256 threads, float4 streams over full N.
// ---------------------------------------------------------------------------
__global__ __launch_bounds__(256) void agg_kernel(
    const float* __restrict__ omega, const float* __restrict__ values,
    float* __restrict__ out) {
  const int b = blockIdx.x & 7;
  const int f0 = (blockIdx.x >> 3) * 4;
  const int t = threadIdx.x;
  const float* om_b = omega + (size_t)b * K_ * N_;
  const float* vb = values + (size_t)b * F_ * N_;

  float acc[4][16];
#pragma unroll
  for (int f = 0; f < 4; ++f)
#pragma unroll
    for (int k = 0; k < 16; ++k) acc[f][k] = 0.f;

  for (int it = 0; it < 32; ++it) {
    const int n0 = (it * 256 + t) * 4;
    float4 om4[16];
#pragma unroll
    for (int k = 0; k < 16; ++k)
      om4[k] = *reinterpret_cast<const float4*>(om_b + (size_t)k * N_ + n0);
#pragma unroll
    for (int f = 0; f < 4; ++f) {
      float4 v4 = *reinterpret_cast<const float4*>(vb + (size_t)(f0 + f) * N_ + n0);
#pragma unroll
      for (int k = 0; k < 16; ++k) {
        acc[f][k] += v4.x * om4[k].x + v4.y * om4[k].y +
                     v4.z * om4[k].z + v4.w * om4[k].w;
      }
    }
  }

  // reduce 64 partials across the block
#pragma unroll
  for (int f = 0; f < 4; ++f)
#pragma unroll
    for (int k = 0; k < 16; ++k) {
      float v = acc[f][k];
#pragma unroll
      for (int off = 32; off > 0; off >>= 1) v += __shfl_xor(v, off, 64);
      acc[f][k] = v;
    }

  __shared__ float red[4][64];
  const int wid = t >> 6, lane = t & 63;
  if (lane == 0) {
#pragma unroll
    for (int f = 0; f < 4; ++f)
#pragma unroll
      for (int k = 0; k < 16; ++k) red[wid][f * 16 + k] = acc[f][k];
  }
  __syncthreads();
  if (t < 64) {
    float s = red[0][t] + red[1][t] + red[2][t] + red[3][t];
    const int f = t >> 4, k = t & 15;
    out[((size_t)b * K_ + k) * F_ + f0 + f] = s;
  }
}

extern "C" void kernel_launch(void* const* d_in, const int* in_sizes, int n_in,
                              void* d_out, int out_size, void* d_ws, size_t ws_size,
                              hipStream_t stream) {
  const float* q = (const float*)d_in[0];
  const float* keys = (const float*)d_in[1];
  const float* values = (const float*)d_in[2];
  float* out = (float*)d_out;
  float* ws = (float*)d_ws;
  float* sims = ws;                         // B*N floats = 1 MB
  float* omega = ws + (size_t)B_ * N_;      // B*K*N floats = 16 MB

  sims_kernel<<<dim3(256), dim3(256), 0, stream>>>(q, keys, sims);
  cascade_kernel<<<dim3(B_), dim3(1024), 0, stream>>>(sims, omega);
  agg_kernel<<<dim3(512), dim3(256), 0, stream>>>(omega, values, out);
}

// Round 2
// 108.727 us; speedup vs baseline: 1.9203x; 1.9203x over previous
//
#include <hip/hip_runtime.h>

#define B_ 8
#define D_ 256
#define N_ 32768
#define F_ 256
#define K_ 16

// ---------------------------------------------------------------------------
// K1: sims[b][n] = -(q[b,:] . keys[b,:,n]) / 16
// 256 blocks x 1024 threads (16 waves/CU). Thread (c,g): c=float4-column,
// g=d-quarter (64 d each). LDS reduce across g. Fixes R0's 4-wave/CU
// latency-hiding problem.
// ---------------------------------------------------------------------------
__global__ __launch_bounds__(1024) void sims_kernel(
    const float* __restrict__ q, const float* __restrict__ keys,
    float* __restrict__ sims) {
  const int b = blockIdx.x >> 5;
  const int chunk = blockIdx.x & 31;
  const int t = threadIdx.x;
  const int c = t & 255;   // float4 column within chunk
  const int g = t >> 8;    // d-quarter 0..3
  __shared__ float qs[D_];
  __shared__ float4 part[4][256];
  if (t < D_) qs[t] = q[b * D_ + t];
  __syncthreads();
  const int n0 = chunk * 1024 + c * 4;
  const float* kp = keys + (size_t)b * D_ * N_ + (size_t)(g * 64) * N_ + n0;
  const float* qg = qs + g * 64;
  float ax = 0.f, ay = 0.f, az = 0.f, aw = 0.f;
#pragma unroll 8
  for (int d = 0; d < 64; ++d) {
    float4 kv = *reinterpret_cast<const float4*>(kp + (size_t)d * N_);
    float qd = qg[d];
    ax += qd * kv.x; ay += qd * kv.y; az += qd * kv.z; aw += qd * kv.w;
  }
  part[g][c] = make_float4(ax, ay, az, aw);
  __syncthreads();
  if (g == 0) {
    float4 p1 = part[1][c], p2 = part[2][c], p3 = part[3][c];
    float4 o;
    o.x = -0.0625f * (ax + p1.x + p2.x + p3.x);
    o.y = -0.0625f * (ay + p1.y + p2.y + p3.y);
    o.z = -0.0625f * (az + p1.z + p2.z + p3.z);
    o.w = -0.0625f * (aw + p1.w + p2.w + p3.w);
    *reinterpret_cast<float4*>(sims + (size_t)b * N_ + n0) = o;
  }
}

// ---------------------------------------------------------------------------
// K2: stats. alpha = softmax(sims); om = softmax(alpha); q = sum(om^2).
// One 1024-thread block per batch, everything in registers.
// ---------------------------------------------------------------------------
__device__ __forceinline__ float block_allreduce(float v, bool is_max,
                                                 float* red) {
  const int t = threadIdx.x;
#pragma unroll
  for (int off = 32; off > 0; off >>= 1) {
    float o = __shfl_xor(v, off, 64);
    v = is_max ? fmaxf(v, o) : (v + o);
  }
  __syncthreads();  // guard previous use of red
  if ((t & 63) == 0) red[t >> 6] = v;
  __syncthreads();
  if (t == 0) {
    float x = red[0];
#pragma unroll
    for (int w = 1; w < 16; ++w) x = is_max ? fmaxf(x, red[w]) : (x + red[w]);
    red[16] = x;
  }
  __syncthreads();
  return red[16];
}

__global__ __launch_bounds__(1024) void stats_kernel(
    const float* __restrict__ sims, float* __restrict__ om,
    float* __restrict__ qout) {
  const int b = blockIdx.x;
  const int t = threadIdx.x;
  const float* s = sims + (size_t)b * N_;
  float* ob = om + (size_t)b * N_;
  __shared__ float red[17];

  float a[32];
#pragma unroll
  for (int j = 0; j < 32; ++j) a[j] = s[t + j * 1024];

  float m = -1e30f;
#pragma unroll
  for (int j = 0; j < 32; ++j) m = fmaxf(m, a[j]);
  m = block_allreduce(m, true, red);

  float sum = 0.f;
#pragma unroll
  for (int j = 0; j < 32; ++j) { a[j] = __expf(a[j] - m); sum += a[j]; }
  const float invZ1 = 1.0f / block_allreduce(sum, false, red);

  // alpha = a*invZ1 in [0, ~2e-3]; om = exp(alpha)/Z2; q = sum(om^2)
  float s1 = 0.f, s2 = 0.f;
#pragma unroll
  for (int j = 0; j < 32; ++j) {
    float f = __expf(a[j] * invZ1);
    a[j] = f;
    s1 += f;
    s2 += f * f;
  }
  const float Z2 = block_allreduce(s1, false, red);
  const float S2 = block_allreduce(s2, false, red);
  const float invZ2 = 1.0f / Z2;
#pragma unroll
  for (int j = 0; j < 32; ++j) ob[t + j * 1024] = a[j] * invZ2;
  if (t == 0) qout[b] = S2 * invZ2 * invZ2;
}

// ---------------------------------------------------------------------------
// K3: A_bf = sum_n om*v, B_bf = sum_n om^2*v;
//     out[b][k][f] = A + k*(q*A - B)   (exact to ~1e-9 rel of omega)
// 512 blocks: b = blockIdx&7 (XCD affinity -> om[b] stays L2-hot), 4 f each.
// ---------------------------------------------------------------------------
__global__ __launch_bounds__(256) void agg_kernel(
    const float* __restrict__ om, const float* __restrict__ values,
    const float* __restrict__ qarr, float* __restrict__ out) {
  const int b = blockIdx.x & 7;
  const int f0 = (blockIdx.x >> 3) * 4;
  const int t = threadIdx.x;
  const float* ob = om + (size_t)b * N_;
  const float* vb = values + (size_t)b * F_ * N_;

  float A[4] = {0.f, 0.f, 0.f, 0.f};
  float Bv[4] = {0.f, 0.f, 0.f, 0.f};

#pragma unroll 2
  for (int it = 0; it < 32; ++it) {
    const int n0 = (it * 256 + t) * 4;
    float4 o4 = *reinterpret_cast<const float4*>(ob + n0);
    float4 o2;
    o2.x = o4.x * o4.x; o2.y = o4.y * o4.y;
    o2.z = o4.z * o4.z; o2.w = o4.w * o4.w;
#pragma unroll
    for (int f = 0; f < 4; ++f) {
      float4 v4 = *reinterpret_cast<const float4*>(vb + (size_t)(f0 + f) * N_ + n0);
      A[f]  += v4.x * o4.x + v4.y * o4.y + v4.z * o4.z + v4.w * o4.w;
      Bv[f] += v4.x * o2.x + v4.y * o2.y + v4.z * o2.z + v4.w * o2.w;
    }
  }

#pragma unroll
  for (int f = 0; f < 4; ++f) {
#pragma unroll
    for (int off = 32; off > 0; off >>= 1) {
      A[f]  += __shfl_xor(A[f], off, 64);
      Bv[f] += __shfl_xor(Bv[f], off, 64);
    }
  }

  __shared__ float red[4][8];
  const int wid = t >> 6, lane = t & 63;
  if (lane == 0) {
#pragma unroll
    for (int f = 0; f < 4; ++f) { red[wid][f] = A[f]; red[wid][4 + f] = Bv[f]; }
  }
  __syncthreads();
  if (t < 64) {
    const int k = t & 15, fi = t >> 4;
    const float Af = red[0][fi] + red[1][fi] + red[2][fi] + red[3][fi];
    const float Bf = red[0][4 + fi] + red[1][4 + fi] + red[2][4 + fi] + red[3][4 + fi];
    const float qb = qarr[b];
    out[((size_t)b * K_ + k) * F_ + f0 + fi] = Af + (float)k * (qb * Af - Bf);
  }
}

extern "C" void kernel_launch(void* const* d_in, const int* in_sizes, int n_in,
                              void* d_out, int out_size, void* d_ws, size_t ws_size,
                              hipStream_t stream) {
  const float* q = (const float*)d_in[0];
  const float* keys = (const float*)d_in[1];
  const float* values = (const float*)d_in[2];
  float* out = (float*)d_out;
  float* ws = (float*)d_ws;
  float* sims = ws;                          // B*N floats = 1 MB
  float* om   = ws + (size_t)B_ * N_;        // B*N floats = 1 MB
  float* qarr = ws + (size_t)2 * B_ * N_;    // B floats

  sims_kernel<<<dim3(256), dim3(1024), 0, stream>>>(q, keys, sims);
  stats_kernel<<<dim3(B_), dim3(1024), 0, stream>>>(sims, om, qarr);
  agg_kernel<<<dim3(512), dim3(256), 0, stream>>>(om, values, qarr, out);
}